// Round 2
// baseline (389.514 us; speedup 1.0000x reference)
//
#include <hip/hip_runtime.h>

#define NPTS 8192
#define DFEAT 256
#define KSEL 33   // rank 0 (self) + 32 neighbors

// ---------------------------------------------------------------------------
// Kernel A: exact top-33 selection per point.
// One block (256 threads) per point i. Each thread owns 32 candidate keys in
// registers: key = (bits(dist) << 32) | j  -> ascending dist, ties -> lower j.
// Distance replicates the XLA-CPU f32 evaluation order exactly:
//   sq   = ((x*x + y*y) + z*z)            (separate rounding, no FMA)
//   dot  = fma(z,z', fma(y,y', x*x'))     (Eigen gebp: acc=0, k-ascending FMA)
//   d2   = (sq_i + sq_j) - (2*dot)
//   dist = sqrtf(max(d2, 0))              (correctly-rounded sqrt, like sqrtss)
// contract(off) so hipcc cannot fuse the mul/add chains into FMAs.
// ---------------------------------------------------------------------------
__global__ __launch_bounds__(256) void knn_select_kernel(const float* __restrict__ pts,
                                                         int* __restrict__ nbr_idx) {
#pragma clang fp contract(off)
    const int i = blockIdx.x;
    const int tid = threadIdx.x;
    const int lane = tid & 63;
    const int wv = tid >> 6;

    __shared__ unsigned long long red[KSEL][4];

    const float xi = pts[i * 3 + 0];
    const float yi = pts[i * 3 + 1];
    const float zi = pts[i * 3 + 2];
    const float sqi = (xi * xi + yi * yi) + zi * zi;

    unsigned long long key[32];
#pragma unroll
    for (int t = 0; t < 32; ++t) {
        const int j = tid + t * 256;
        const float xj = pts[j * 3 + 0];
        const float yj = pts[j * 3 + 1];
        const float zj = pts[j * 3 + 2];
        const float sqj = (xj * xj + yj * yj) + zj * zj;
        const float dot = __builtin_fmaf(zi, zj, __builtin_fmaf(yi, yj, xi * xj));
        const float d2 = (sqi + sqj) - (2.0f * dot);
        const float dist = sqrtf(fmaxf(d2, 0.0f));
        key[t] = (((unsigned long long)__float_as_uint(dist)) << 32) | (unsigned)j;
    }

    unsigned long long cand = key[0];
#pragma unroll
    for (int t = 1; t < 32; ++t) cand = key[t] < cand ? key[t] : cand;

    for (int k = 0; k < KSEL; ++k) {
        unsigned long long m = cand;
#pragma unroll
        for (int s = 1; s < 64; s <<= 1) {
            const unsigned long long o = __shfl_xor(m, s, 64);
            m = o < m ? o : m;
        }
        if (lane == 0) red[k][wv] = m;
        __syncthreads();
        const unsigned long long w0 = red[k][0], w1 = red[k][1];
        const unsigned long long w2 = red[k][2], w3 = red[k][3];
        const unsigned long long a = w0 < w1 ? w0 : w1;
        const unsigned long long b = w2 < w3 ? w2 : w3;
        const unsigned long long winner = a < b ? a : b;
        if (k > 0 && tid == 0)
            nbr_idx[i * 32 + (k - 1)] = (int)(unsigned)(winner & 0xFFFFFFFFull);
        if (cand == winner) {
            unsigned long long nc = ~0ull;
#pragma unroll
            for (int t = 0; t < 32; ++t) {
                const unsigned long long kt = key[t];
                const bool take = (kt > winner) & (kt < nc);
                nc = take ? kt : nc;
            }
            cand = nc;
        }
    }
}

// ---------------------------------------------------------------------------
// Kernel B: gather + copy. 57 output rows per point:
//   t==0        -> out0 (copy of feats row i)
//   t in [1,9)  -> out1 (scale 8),  neighbor k=t-1
//   t in [9,25) -> out2 (scale 16), neighbor k=t-9
//   t in [25,57)-> out3 (scale 32), neighbor k=t-25
// One wave per 256-float row (64 lanes x float4 = 1KB, coalesced).
// ---------------------------------------------------------------------------
__global__ __launch_bounds__(256) void gather_kernel(const float* __restrict__ feats,
                                                     const int* __restrict__ nbr_idx,
                                                     float* __restrict__ out) {
    const unsigned lane = threadIdx.x & 63u;
    const unsigned wv = threadIdx.x >> 6;
    const unsigned r = blockIdx.x * 4u + wv;
    const unsigned TOT = NPTS * 57u;
    if (r >= TOT) return;
    const unsigned i = r / 57u;
    const unsigned t = r - i * 57u;

    const unsigned long long S1 = (unsigned long long)NPTS * 256ull;
    const unsigned long long S2 = S1 + (unsigned long long)NPTS * 2048ull;
    const unsigned long long S3 = S2 + (unsigned long long)NPTS * 4096ull;

    unsigned src;
    unsigned long long dst;
    if (t == 0u) {
        src = i;
        dst = (unsigned long long)i * 256ull;
    } else if (t < 9u) {
        const unsigned k = t - 1u;
        src = (unsigned)nbr_idx[i * 32u + k];
        dst = S1 + (unsigned long long)i * 2048ull + (unsigned long long)k * 256ull;
    } else if (t < 25u) {
        const unsigned k = t - 9u;
        src = (unsigned)nbr_idx[i * 32u + k];
        dst = S2 + (unsigned long long)i * 4096ull + (unsigned long long)k * 256ull;
    } else {
        const unsigned k = t - 25u;
        src = (unsigned)nbr_idx[i * 32u + k];
        dst = S3 + (unsigned long long)i * 8192ull + (unsigned long long)k * 256ull;
    }

    const float4* s = (const float4*)(feats + (unsigned long long)src * 256ull);
    float4* d = (float4*)(out + dst);
    d[lane] = s[lane];
}

extern "C" void kernel_launch(void* const* d_in, const int* in_sizes, int n_in,
                              void* d_out, int out_size, void* d_ws, size_t ws_size,
                              hipStream_t stream) {
    const float* feats = (const float*)d_in[0];   // (8192, 256) f32
    const float* pts = (const float*)d_in[1];     // (8192, 3)   f32
    // d_in[2] = f_masks (unused by the reference computation)

    int* nbr = (int*)d_ws;                        // 8192 * 32 ints = 1 MB

    knn_select_kernel<<<NPTS, 256, 0, stream>>>(pts, nbr);

    const unsigned rows = NPTS * 57u;             // 466944 rows
    gather_kernel<<<(rows + 3u) / 4u, 256, 0, stream>>>(feats, nbr, (float*)d_out);
}

// Round 3
// 382.860 us; speedup vs baseline: 1.0174x; 1.0174x over previous
//
#include <hip/hip_runtime.h>

#define NPTS 8192
#define DFEAT 256
#define KSEL 33   // rank 0 (self) + 32 neighbors

// ---------------------------------------------------------------------------
// Prep: pts4[j] = (x, y, z, sq) with sq = (x*x + y*y) + z*z, exact same
// rounding order as the reference (contract off, separate mul/add).
// ---------------------------------------------------------------------------
__global__ __launch_bounds__(256) void prep_kernel(const float* __restrict__ pts,
                                                   float4* __restrict__ pts4) {
#pragma clang fp contract(off)
    const int j = blockIdx.x * 256 + threadIdx.x;
    const float x = pts[j * 3 + 0];
    const float y = pts[j * 3 + 1];
    const float z = pts[j * 3 + 2];
    const float sq = (x * x + y * y) + z * z;
    pts4[j] = make_float4(x, y, z, sq);
}

// ---------------------------------------------------------------------------
// Kernel A: exact top-33 selection per point, u32-key edition.
// One block (256 threads) per point i. Thread owns 32 dist-bit u32s in regs;
// j = tid + t*256 is derived, not stored -> no u64 keys, no spills.
// Distance replicates XLA-CPU evaluation order exactly (verified round 2):
//   dot  = fma(z,z', fma(y,y', x*x'))
//   d2   = (sq_i + sq_j) - (2*dot)
//   dist = sqrtf(max(d2,0))   (correctly rounded)
// Per round: 6-step u32 wave min + ballot j-resolve (rare tie -> 2nd u32
// reduce), one packed u64 (d<<32|j) per wave to LDS, 4-way min -> winner.
// Ordering is lexicographic (dist, j), bit-identical to the u64-key version.
// ---------------------------------------------------------------------------
__global__ __launch_bounds__(256) void knn_select_kernel(const float4* __restrict__ pts4,
                                                         int* __restrict__ nbr_idx) {
#pragma clang fp contract(off)
    const int i = blockIdx.x;
    const int tid = threadIdx.x;
    const int lane = tid & 63;
    const int wv = tid >> 6;

    __shared__ unsigned long long red[KSEL][4];

    const float4 pi = pts4[i];
    const float xi = pi.x, yi = pi.y, zi = pi.z, sqi = pi.w;

    unsigned d[32];
#pragma unroll
    for (int t = 0; t < 32; ++t) {
        const int j = tid + t * 256;
        const float4 pj = pts4[j];
        const float dot = __builtin_fmaf(zi, pj.z, __builtin_fmaf(yi, pj.y, xi * pj.x));
        const float d2 = (sqi + pj.w) - (2.0f * dot);
        d[t] = __float_as_uint(sqrtf(fmaxf(d2, 0.0f)));
    }

    // per-thread lexicographic (d, t)-min; t ascending + strict < keeps min j
    unsigned cand_d = d[0];
    int cand_t = 0;
#pragma unroll
    for (int t = 1; t < 32; ++t) {
        if (d[t] < cand_d) { cand_d = d[t]; cand_t = t; }
    }

    for (int k = 0; k < KSEL; ++k) {
        // --- wave min over u32 dist bits (6 DS + 6 v_min) ---
        unsigned m = cand_d;
#pragma unroll
        for (int s = 1; s < 64; s <<= 1) {
            const unsigned o = __shfl_xor(m, s, 64);
            m = o < m ? o : m;
        }
        // --- resolve winning j within the wave ---
        const unsigned my_j = (unsigned)(tid + (cand_t << 8));
        const unsigned long long bal = __ballot(cand_d == m);
        unsigned wj_wave;
        if (__popcll(bal) == 1ull) {
            const int l = (int)__ffsll((long long)bal) - 1;
            wj_wave = __shfl(my_j, l, 64);
        } else {
            // rare: multiple lanes tie on dist bits -> min j among them
            unsigned jm = (cand_d == m) ? my_j : 0xFFFFFFFFu;
#pragma unroll
            for (int s = 1; s < 64; s <<= 1) {
                const unsigned o = __shfl_xor(jm, s, 64);
                jm = o < jm ? o : jm;
            }
            wj_wave = jm;
        }
        // --- block combine: one packed key per wave ---
        if (lane == 0) red[k][wv] = (((unsigned long long)m) << 32) | wj_wave;
        __syncthreads();
        const unsigned long long w0 = red[k][0], w1 = red[k][1];
        const unsigned long long w2 = red[k][2], w3 = red[k][3];
        const unsigned long long a = w0 < w1 ? w0 : w1;
        const unsigned long long b = w2 < w3 ? w2 : w3;
        const unsigned long long winner = a < b ? a : b;
        const unsigned wd = (unsigned)(winner >> 32);
        const unsigned wj = (unsigned)winner;

        if (k > 0 && tid == 0)
            nbr_idx[i * 32 + (k - 1)] = (int)wj;

        // --- only the winning thread rescans (j unique -> exactly one) ---
        if (cand_d == wd && my_j == wj) {
            unsigned best_d = 0xFFFFFFFFu;
            int best_t = 0;
#pragma unroll
            for (int t = 0; t < 32; ++t) {
                const unsigned jt = (unsigned)(tid + (t << 8));
                const bool valid = (d[t] > wd) | ((d[t] == wd) & (jt > wj));
                if (valid && d[t] < best_d) { best_d = d[t]; best_t = t; }
            }
            cand_d = best_d;
            cand_t = best_t;
        }
    }
}

// ---------------------------------------------------------------------------
// Kernel B: gather + copy. 57 output rows per point:
//   t==0        -> out0 (copy of feats row i)
//   t in [1,9)  -> out1 (scale 8),  neighbor k=t-1
//   t in [9,25) -> out2 (scale 16), neighbor k=t-9
//   t in [25,57)-> out3 (scale 32), neighbor k=t-25
// One wave per 256-float row (64 lanes x float4 = 1KB, coalesced).
// ---------------------------------------------------------------------------
__global__ __launch_bounds__(256) void gather_kernel(const float* __restrict__ feats,
                                                     const int* __restrict__ nbr_idx,
                                                     float* __restrict__ out) {
    const unsigned lane = threadIdx.x & 63u;
    const unsigned wv = threadIdx.x >> 6;
    const unsigned r = blockIdx.x * 4u + wv;
    const unsigned TOT = NPTS * 57u;
    if (r >= TOT) return;
    const unsigned i = r / 57u;
    const unsigned t = r - i * 57u;

    const unsigned long long S1 = (unsigned long long)NPTS * 256ull;
    const unsigned long long S2 = S1 + (unsigned long long)NPTS * 2048ull;
    const unsigned long long S3 = S2 + (unsigned long long)NPTS * 4096ull;

    unsigned src;
    unsigned long long dst;
    if (t == 0u) {
        src = i;
        dst = (unsigned long long)i * 256ull;
    } else if (t < 9u) {
        const unsigned k = t - 1u;
        src = (unsigned)nbr_idx[i * 32u + k];
        dst = S1 + (unsigned long long)i * 2048ull + (unsigned long long)k * 256ull;
    } else if (t < 25u) {
        const unsigned k = t - 9u;
        src = (unsigned)nbr_idx[i * 32u + k];
        dst = S2 + (unsigned long long)i * 4096ull + (unsigned long long)k * 256ull;
    } else {
        const unsigned k = t - 25u;
        src = (unsigned)nbr_idx[i * 32u + k];
        dst = S3 + (unsigned long long)i * 8192ull + (unsigned long long)k * 256ull;
    }

    const float4* s = (const float4*)(feats + (unsigned long long)src * 256ull);
    float4* dp = (float4*)(out + dst);
    dp[lane] = s[lane];
}

extern "C" void kernel_launch(void* const* d_in, const int* in_sizes, int n_in,
                              void* d_out, int out_size, void* d_ws, size_t ws_size,
                              hipStream_t stream) {
    const float* feats = (const float*)d_in[0];   // (8192, 256) f32
    const float* pts = (const float*)d_in[1];     // (8192, 3)   f32
    // d_in[2] = f_masks (unused by the reference computation)

    float4* pts4 = (float4*)d_ws;                         // 128 KB
    int* nbr = (int*)((char*)d_ws + NPTS * 16);           // 1 MB

    prep_kernel<<<NPTS / 256, 256, 0, stream>>>(pts, pts4);
    knn_select_kernel<<<NPTS, 256, 0, stream>>>(pts4, nbr);

    const unsigned rows = NPTS * 57u;             // 466944 rows
    gather_kernel<<<(rows + 3u) / 4u, 256, 0, stream>>>(feats, nbr, (float*)d_out);
}

// Round 4
// 226.299 us; speedup vs baseline: 1.7212x; 1.6918x over previous
//
#include <hip/hip_runtime.h>

#define NPTS 8192
#define KSEL 33    // rank 0 (self) + 32 neighbors
#define SCAP 512   // survivor capacity (analysis: c <= ~64 always)

// ---------------------------------------------------------------------------
// Prep: pts4[j] = (x, y, z, sq), sq = (x*x + y*y) + z*z in exact reference
// rounding order (contract off, separate mul/add).
// ---------------------------------------------------------------------------
__global__ __launch_bounds__(256) void prep_kernel(const float* __restrict__ pts,
                                                   float4* __restrict__ pts4) {
#pragma clang fp contract(off)
    const int j = blockIdx.x * 256 + threadIdx.x;
    const float x = pts[j * 3 + 0];
    const float y = pts[j * 3 + 1];
    const float z = pts[j * 3 + 2];
    const float sq = (x * x + y * y) + z * z;
    pts4[j] = make_float4(x, y, z, sq);
}

// ---------------------------------------------------------------------------
// Fused exact-kNN + gather. One block (256 threads) per point i.
//
// 1) dist loop: thread owns j = tid + t*256, t=0..31. Exact reference bits:
//    dot = fma(z,z', fma(y,y', x*x')); d2 = (sq_i+sq_j) - 2*dot;
//    dist = sqrtf(max(d2,0)) (correctly rounded). Track per-thread 2 smallest.
// 2) phase A (barrier-free): per wave, 33 rounds of 6-shfl u32 min over the
//    (m1,m2) lists -> Tw = 33rd-smallest of the wave's 2-min multiset.
//    SAFE upper bound on the true 33rd distance (threads owning >=3 winners
//    only push Tw up). T = min over 4 waves; guarantees >= 33 survivors.
// 3) compact d <= T into LDS (wave prefix sum + one LDS atomic per wave).
// 4) rank: all-pairs compare on u64 key (dist<<32 | j) = exact lexicographic
//    (dist, j) order, identical to lax.top_k tie-breaking. ranks 1..32 ->
//    jlist. Survivor set provably contains the global top-33, and every
//    non-survivor has a larger key, so survivor-rank == global rank.
// 5) gather: 57 rows of 1 KB (copy row + 8/16/32-scale neighbor rows),
//    one wave per row, float4 coalesced.
// ---------------------------------------------------------------------------
__global__ __launch_bounds__(256) void knn_fused_kernel(const float4* __restrict__ pts4,
                                                        const float* __restrict__ feats,
                                                        float* __restrict__ out) {
#pragma clang fp contract(off)
    const int i = blockIdx.x;
    const int tid = threadIdx.x;
    const int lane = tid & 63;
    const int wv = tid >> 6;

    __shared__ unsigned red[4];
    __shared__ int sh_cnt;
    __shared__ unsigned long long S[SCAP];
    __shared__ unsigned jlist[32];

    const float4 pi = pts4[i];

    unsigned d[32];
    unsigned m1 = 0xFFFFFFFFu, m2 = 0xFFFFFFFFu;
#pragma unroll
    for (int t = 0; t < 32; ++t) {
        const int j = tid + t * 256;
        const float4 pj = pts4[j];
        const float dot = __builtin_fmaf(pi.z, pj.z, __builtin_fmaf(pi.y, pj.y, pi.x * pj.x));
        const float d2 = (pi.w + pj.w) - (2.0f * dot);
        const unsigned db = __float_as_uint(sqrtf(fmaxf(d2, 0.0f)));
        d[t] = db;
        const unsigned lo = db < m1 ? db : m1;
        const unsigned hi = db < m1 ? m1 : db;
        m1 = lo;
        m2 = hi < m2 ? hi : m2;
    }
    if (tid == 0) sh_cnt = 0;

    // --- phase A: wave-local 33 extraction rounds on (m1,m2), u32 only ---
    unsigned Tw = 0;
    for (int k = 0; k < KSEL; ++k) {
        unsigned m = m1;
#pragma unroll
        for (int s = 1; s < 64; s <<= 1) {
            const unsigned o = __shfl_xor(m, s, 64);
            m = o < m ? o : m;
        }
        // all lanes whose head matches the min advance (dup-ties only raise T)
        if (m1 == m) { m1 = m2; m2 = 0xFFFFFFFFu; }
        Tw = m;
    }
    if (lane == 0) red[wv] = Tw;
    __syncthreads();
    unsigned T = red[0];
    T = red[1] < T ? red[1] : T;
    T = red[2] < T ? red[2] : T;
    T = red[3] < T ? red[3] : T;

    // --- compact survivors (d <= T) into LDS ---
    int n = 0;
#pragma unroll
    for (int t = 0; t < 32; ++t) n += (d[t] <= T) ? 1 : 0;

    int incl = n;
#pragma unroll
    for (int s = 1; s < 64; s <<= 1) {
        const int o = __shfl_up(incl, s, 64);
        if (lane >= s) incl += o;
    }
    int base = 0;
    if (lane == 63) base = atomicAdd(&sh_cnt, incl);
    base = __shfl(base, 63, 64);
    int ptr = base + incl - n;
#pragma unroll
    for (int t = 0; t < 32; ++t) {
        if (d[t] <= T) {
            if (ptr < SCAP)
                S[ptr] = (((unsigned long long)d[t]) << 32) | (unsigned)(tid + t * 256);
            ++ptr;
        }
    }
    __syncthreads();

    // --- exact global rank among survivors ---
    const int c = sh_cnt < SCAP ? sh_cnt : SCAP;
    for (int q = tid; q < c; q += 256) {
        const unsigned long long key = S[q];
        int rank = 0;
        for (int u = 0; u < c; ++u) rank += (S[u] < key) ? 1 : 0;
        if (rank >= 1 && rank < KSEL) jlist[rank - 1] = (unsigned)key;
    }
    __syncthreads();

    // --- gather: 57 rows per point, one wave per row ---
    const unsigned long long O1 = (unsigned long long)NPTS * 256ull;
    const unsigned long long O2 = O1 + (unsigned long long)NPTS * 2048ull;
    const unsigned long long O3 = O2 + (unsigned long long)NPTS * 4096ull;

    for (int r = wv; r < 57; r += 4) {
        unsigned src;
        unsigned long long dst;
        if (r == 0) {
            src = (unsigned)i;
            dst = (unsigned long long)i * 256ull;
        } else if (r < 9) {
            const int k = r - 1;
            src = jlist[k];
            dst = O1 + (unsigned long long)i * 2048ull + (unsigned long long)k * 256ull;
        } else if (r < 25) {
            const int k = r - 9;
            src = jlist[k];
            dst = O2 + (unsigned long long)i * 4096ull + (unsigned long long)k * 256ull;
        } else {
            const int k = r - 25;
            src = jlist[k];
            dst = O3 + (unsigned long long)i * 8192ull + (unsigned long long)k * 256ull;
        }
        const float4* s4 = (const float4*)(feats + (unsigned long long)src * 256ull);
        float4* d4 = (float4*)(out + dst);
        d4[lane] = s4[lane];
    }
}

extern "C" void kernel_launch(void* const* d_in, const int* in_sizes, int n_in,
                              void* d_out, int out_size, void* d_ws, size_t ws_size,
                              hipStream_t stream) {
    const float* feats = (const float*)d_in[0];   // (8192, 256) f32
    const float* pts = (const float*)d_in[1];     // (8192, 3)   f32
    // d_in[2] = f_masks (all ones; unused by the reference computation)

    float4* pts4 = (float4*)d_ws;                 // 128 KB scratch

    prep_kernel<<<NPTS / 256, 256, 0, stream>>>(pts, pts4);
    knn_fused_kernel<<<NPTS, 256, 0, stream>>>(pts4, feats, (float*)d_out);
}

// Round 6
// 167.553 us; speedup vs baseline: 2.3247x; 1.3506x over previous
//
#include <hip/hip_runtime.h>

#define NPTS 8192
#define KSEL 33    // rank 0 (self) + 32 neighbors
#define SCAP 512   // survivor capacity (c is ~40-80 in practice)

typedef float vf4 __attribute__((ext_vector_type(4)));  // native vec for NT store

// ---------------------------------------------------------------------------
// Prep: pts4[j] = (x, y, z, sq), sq = (x*x + y*y) + z*z in exact reference
// rounding order (contract off, separate mul/add).
// ---------------------------------------------------------------------------
__global__ __launch_bounds__(256) void prep_kernel(const float* __restrict__ pts,
                                                   float4* __restrict__ pts4) {
#pragma clang fp contract(off)
    const int j = blockIdx.x * 256 + threadIdx.x;
    const float x = pts[j * 3 + 0];
    const float y = pts[j * 3 + 1];
    const float z = pts[j * 3 + 2];
    const float sq = (x * x + y * y) + z * z;
    pts4[j] = make_float4(x, y, z, sq);
}

// ---------------------------------------------------------------------------
// Fused exact-kNN + gather. One block (256 threads) per point i.
//
// 1) dist loop (NO sqrt): thread owns j = tid + t*256. Exact reference d2:
//    dot = fma(z,z', fma(y,y', x*x')); d2c = max((sq_i+sq_j) - 2*dot, 0).
//    Track per-thread 2 smallest d2-bit values (m1 <= m2).
// 2) per-wave BALLOT BINARY SEARCH for the 33rd smallest of the 128-value
//    {m1,m2} multiset -> Tw (d2 bits). Safe upper bound of the wave's (hence
//    global) 33rd-smallest d2. T = min over the 4 waves (one barrier).
// 3) widen T to the sqrt-closure: s = CR_sqrt(T) >= true 33rd dist (order
//    statistics commute with the monotone CR sqrt). T2 = sup-bits{x :
//    CR_sqrt(x) <= s} (+2 ulp slack). Every element with dist <= s survives;
//    every non-survivor has dist > s strictly -> cannot be top-33 even by
//    tie-break. Bit-identical selection to the all-sqrt version.
// 4) compact survivors (d2 <= T2) into LDS, computing CR sqrtf only for them;
//    key = (dist_bits<<32 | j) = lax.top_k's (dist, index) order.
// 5) all-pairs rank among c survivors; ranks 1..32 -> jlist.
// 6) gather: 57 rows x 1 KB per point, one wave per row, float4, NT stores.
// ---------------------------------------------------------------------------
__global__ __launch_bounds__(256) void knn_fused_kernel(const float4* __restrict__ pts4,
                                                        const float* __restrict__ feats,
                                                        float* __restrict__ out) {
#pragma clang fp contract(off)
    const int i = blockIdx.x;
    const int tid = threadIdx.x;
    const int lane = tid & 63;
    const int wv = tid >> 6;

    __shared__ unsigned red[4];
    __shared__ int sh_cnt;
    __shared__ unsigned long long S[SCAP];
    __shared__ unsigned jlist[32];

    const float4 pi = pts4[i];

    unsigned d[32];                       // clamped-d2 bits per owned j
    unsigned m1 = 0xFFFFFFFFu, m2 = 0xFFFFFFFFu;
#pragma unroll
    for (int t = 0; t < 32; ++t) {
        const int j = tid + t * 256;
        const float4 pj = pts4[j];
        const float dot = __builtin_fmaf(pi.z, pj.z, __builtin_fmaf(pi.y, pj.y, pi.x * pj.x));
        const float d2 = (pi.w + pj.w) - (2.0f * dot);
        const unsigned db = __float_as_uint(fmaxf(d2, 0.0f));
        d[t] = db;
        const unsigned mx = db > m1 ? db : m1;   // max(db, m1)
        m1 = db < m1 ? db : m1;                  // min
        m2 = mx < m2 ? mx : m2;                  // 2nd smallest
    }
    if (tid == 0) sh_cnt = 0;

    // --- per-wave ballot binary search: exact 33rd smallest of {m1,m2} ---
    unsigned blo = 0u, bhi = 0x7F800000u;        // finite non-neg float bits
    while (blo < bhi) {
        const unsigned mid = (blo + bhi) >> 1;
        const int cnt = __popcll(__ballot(m1 <= mid)) + __popcll(__ballot(m2 <= mid));
        if (cnt >= KSEL) bhi = mid; else blo = mid + 1u;
    }
    if (lane == 0) red[wv] = bhi;
    __syncthreads();
    unsigned T = red[0];
    T = red[1] < T ? red[1] : T;
    T = red[2] < T ? red[2] : T;
    T = red[3] < T ? red[3] : T;

    // --- widen to sqrt-closure (conservative, provably inclusive) ---
    const float s = sqrtf(__uint_as_float(T));               // CR sqrt
    const float snx = __uint_as_float(__float_as_uint(s) + 1u);
    const unsigned T2 = __float_as_uint(__fmul_rn(snx, snx)) + 2u;

    // --- compact survivors into LDS (CR sqrt only here) ---
    int n = 0;
#pragma unroll
    for (int t = 0; t < 32; ++t) n += (d[t] <= T2) ? 1 : 0;

    int incl = n;
#pragma unroll
    for (int sh = 1; sh < 64; sh <<= 1) {
        const int o = __shfl_up(incl, sh, 64);
        if (lane >= sh) incl += o;
    }
    int base = 0;
    if (lane == 63) base = atomicAdd(&sh_cnt, incl);
    base = __shfl(base, 63, 64);
    int ptr = base + incl - n;
#pragma unroll
    for (int t = 0; t < 32; ++t) {
        if (d[t] <= T2) {
            const unsigned db = __float_as_uint(sqrtf(__uint_as_float(d[t])));
            if (ptr < SCAP)
                S[ptr] = (((unsigned long long)db) << 32) | (unsigned)(tid + t * 256);
            ++ptr;
        }
    }
    __syncthreads();

    // --- exact global rank among survivors (keys unique via j) ---
    const int c = sh_cnt < SCAP ? sh_cnt : SCAP;
    for (int q = tid; q < c; q += 256) {
        const unsigned long long key = S[q];
        int rank = 0;
        for (int u = 0; u < c; ++u) rank += (S[u] < key) ? 1 : 0;
        if (rank >= 1 && rank < KSEL) jlist[rank - 1] = (unsigned)key;
    }
    __syncthreads();

    // --- gather: 57 rows per point, one wave per row, NT float4 stores ---
    const unsigned long long O1 = (unsigned long long)NPTS * 256ull;
    const unsigned long long O2 = O1 + (unsigned long long)NPTS * 2048ull;
    const unsigned long long O3 = O2 + (unsigned long long)NPTS * 4096ull;

    for (int r = wv; r < 57; r += 4) {
        unsigned src;
        unsigned long long dst;
        if (r == 0) {
            src = (unsigned)i;
            dst = (unsigned long long)i * 256ull;
        } else if (r < 9) {
            const int k = r - 1;
            src = jlist[k];
            dst = O1 + (unsigned long long)i * 2048ull + (unsigned long long)k * 256ull;
        } else if (r < 25) {
            const int k = r - 9;
            src = jlist[k];
            dst = O2 + (unsigned long long)i * 4096ull + (unsigned long long)k * 256ull;
        } else {
            const int k = r - 25;
            src = jlist[k];
            dst = O3 + (unsigned long long)i * 8192ull + (unsigned long long)k * 256ull;
        }
        const vf4* s4 = (const vf4*)(feats + (unsigned long long)src * 256ull);
        vf4* d4 = (vf4*)(out + dst);
        __builtin_nontemporal_store(s4[lane], &d4[lane]);
    }
}

extern "C" void kernel_launch(void* const* d_in, const int* in_sizes, int n_in,
                              void* d_out, int out_size, void* d_ws, size_t ws_size,
                              hipStream_t stream) {
    const float* feats = (const float*)d_in[0];   // (8192, 256) f32
    const float* pts = (const float*)d_in[1];     // (8192, 3)   f32
    // d_in[2] = f_masks (all ones; unused by the reference computation)

    float4* pts4 = (float4*)d_ws;                 // 128 KB scratch

    prep_kernel<<<NPTS / 256, 256, 0, stream>>>(pts, pts4);
    knn_fused_kernel<<<NPTS, 256, 0, stream>>>(pts4, feats, (float*)d_out);
}